// Round 7
// baseline (214.898 us; speedup 1.0000x reference)
//
#include <hip/hip_runtime.h>
#include <hip/hip_bf16.h>

// Problem constants (from reference)
#define BATCH 8
#define NH    8
#define HD    32
#define WIN   512    // 64 x 8 tokens per vertical-stripe window
#define DIM   256
#define RESO  64
#define SEQL  4096
#define VSTRIDE 520  // Vt padded token stride (bf16 elements)
#define WPAD  264    // proj W LDS row stride (bf16 elements)

#define LOG2E 1.44269504088896340736f

extern "C" __device__ float __ocml_native_exp2_f32(float);   // raw v_exp_f32

typedef __attribute__((ext_vector_type(8))) short short8;   // 8 bf16 (4 VGPRs) MFMA A/B frag
typedef __attribute__((ext_vector_type(4))) float floatx4;  // MFMA C/D frag

__device__ __forceinline__ unsigned short f2bf(float f) {
    union { float f; unsigned int i; } x; x.f = f;
    unsigned int r = x.i + 0x7fff + ((x.i >> 16) & 1);   // round-to-nearest-even
    return (unsigned short)(r >> 16);
}
__device__ __forceinline__ float bf2f(unsigned short u) {
    union { unsigned int i; float f; } x; x.i = ((unsigned int)u) << 16; return x.f;
}
__device__ __forceinline__ unsigned int pk2(float lo, float hi) {      // RNE pack
    return ((unsigned int)f2bf(hi) << 16) | (unsigned int)f2bf(lo);
}
__device__ __forceinline__ unsigned int pk2t(float lo, float hi) {     // truncation pack, 1 v_perm
    union { float f; unsigned int i; } a, b; a.f = lo; b.f = hi;
    return __builtin_amdgcn_perm(b.i, a.i, 0x07060302);                // {hi[3],hi[2],lo[3],lo[2]}
}

union FragU {
    unsigned int  u[4];
    unsigned short us[8];
    short8        s;
    ushort4       v4[2];
};

// ---------------------------------------------------------------------------
// MFMA flash attention + LePE. Grid: 512 blocks (64 win x 8 heads) x 512 thr
// (8 waves). Wave w owns query rows w*64..w*64+63 (4 q-tiles of 16).
//
// ROUND-7 EXPERIMENT: register-budget pinning + breadth-first inner loop.
// HW occupancy is fixed at 4 waves/SIMD (LDS 66 KiB -> 2 blocks/CU; r1/r3/r4
// proved any structure that needs more regs/waves spills).  Previous builds
// compiled to 64 VGPR because hipcc's heuristic chases 8 waves/SIMD that LDS
// makes unreachable — serializing the 4 independent qq chains through a
// 64-reg window (why r2's prefetch was null).  amdgpu_waves_per_eu(4,4)
// pins the budget at 128 regs; the inner loop is restructured breadth-first
// over qq-PAIRS (4 QK MFMAs -> 16 exps -> 2 packs -> 4 PV MFMAs) to spend
// those regs on producer->consumer distance.  Per-value arithmetic order is
// unchanged -> bit-identical output (absmax pinned at 0.015625).
// ---------------------------------------------------------------------------
__global__ __attribute__((amdgpu_flat_work_group_size(512, 512)))
__attribute__((amdgpu_waves_per_eu(4, 4)))
void attn_mfma_kernel(const float* __restrict__ qkv,
                      const float* __restrict__ scale_p,
                      const float* __restrict__ conv_w,
                      const float* __restrict__ conv_b,
                      unsigned short* __restrict__ X)
{
    __shared__ alignas(16) unsigned short Klds[WIN * HD];      // swizzled 16B chunks
    __shared__ alignas(16) unsigned short Vt[HD * VSTRIDE];    // V^T, padded
    __shared__ float cw[HD * 9];
    __shared__ float cb[HD];

    // XCD swizzle (512 = 8*64, bijective): blocks {x, x+8, ...} -> wh [64x,64x+64)
    const int wh_raw = blockIdx.x;
    const int wh   = ((wh_raw & 7) << 6) | (wh_raw >> 3);
    const int bw   = wh >> 3;        // global window 0..63
    const int head = wh & 7;
    const int b    = bw >> 3;
    const int wx   = bw & 7;
    const int tid  = threadIdx.x;

    const float scale = scale_p[0] * LOG2E;    // log2-domain logits
    const size_t plane = (size_t)BATCH * SEQL * DIM;
    const float* qg = qkv;
    const float* kg = qkv + plane;
    const float* vg = qkv + 2 * plane;

    // ---- Stage K (bf16 trunc, XOR-swizzled 16B chunks); static trip=4 ----
    #pragma unroll
    for (int kk = 0; kk < 4; ++kk) {
        const int idx = tid + kk * 512;
        const int t = idx >> 2, c8 = idx & 3;
        const size_t goff = ((size_t)b * SEQL + (size_t)(t >> 3) * RESO + wx * 8 + (t & 7)) * DIM
                          + head * HD + c8 * 8;
        const float4 k0 = *(const float4*)(kg + goff);
        const float4 k1 = *(const float4*)(kg + goff + 4);
        uint4 pk;
        pk.x = pk2t(k0.x, k0.y); pk.y = pk2t(k0.z, k0.w);
        pk.z = pk2t(k1.x, k1.y); pk.w = pk2t(k1.z, k1.w);
        const int p = c8 ^ ((t >> 1) & 3);
        *(uint4*)&Klds[t * HD + p * 8] = pk;
    }
    // ---- Stage V^T (bf16 RNE, padded stride); static trip=16 ----
    #pragma unroll
    for (int kk = 0; kk < 16; ++kk) {
        const int idx = tid + kk * 512;
        const int ch = idx & 31, tp = idx >> 5;
        const int t = tp * 2;
        const size_t goff = ((size_t)b * SEQL + (size_t)(t >> 3) * RESO + wx * 8 + (t & 7)) * DIM
                          + head * HD + ch;
        const float v0 = vg[goff];
        const float v1 = vg[goff + DIM];       // token t+1 (same image row)
        *(unsigned int*)&Vt[ch * VSTRIDE + t] = pk2(v0, v1);
    }
    if (tid < HD * 9) cw[tid] = conv_w[head * HD * 9 + tid];
    if (tid < HD)     cb[tid] = conv_b[head * HD + tid];

    const int lane = tid & 63, wid = tid >> 6;
    const int q4 = lane >> 4, nn = lane & 15;
    const int qbase = wid * 64;
    const bool mwin = (wx == 7);

    // ---- Q B-frags (4 q-tiles), pre-scaled, bf16 trunc; before barrier so
    //      the global-load latency overlaps the staging barrier wait ----
    short8 qf[4];
    #pragma unroll
    for (int qq = 0; qq < 4; ++qq) {
        const int t = qbase + qq * 16 + nn;
        const size_t goff = ((size_t)b * SEQL + (size_t)(t >> 3) * RESO + wx * 8 + (t & 7)) * DIM
                          + head * HD + q4 * 8;
        const float4 a = *(const float4*)(qg + goff);
        const float4 c = *(const float4*)(qg + goff + 4);
        FragU f;
        f.u[0] = pk2t(a.x * scale, a.y * scale);
        f.u[1] = pk2t(a.z * scale, a.w * scale);
        f.u[2] = pk2t(c.x * scale, c.y * scale);
        f.u[3] = pk2t(c.z * scale, c.w * scale);
        qf[qq] = f.s;
    }
    __syncthreads();

    // mask add (only stripe wx==7): key group vs query group, lane-constant
    float mk[4];
    #pragma unroll
    for (int r = 0; r < 4; ++r) {
        const bool kgrp = (((q4 * 4 + r) & 7) < 4);
        const bool qgrp = ((nn & 7) < 4);
        mk[r] = (kgrp != qgrp) ? (-100.f * LOG2E) : 0.f;
    }

    floatx4 acc[4][2];
    #pragma unroll
    for (int qq = 0; qq < 4; ++qq) {
        acc[qq][0] = (floatx4){0.f, 0.f, 0.f, 0.f};
        acc[qq][1] = (floatx4){0.f, 0.f, 0.f, 0.f};
    }
    float rs[4] = {0.f, 0.f, 0.f, 0.f};
    const floatx4 zf = (floatx4){0.f, 0.f, 0.f, 0.f};

    // K-chunk swizzle is kc-invariant: (t>>1)&3 == (nn>>1)&3 for all chunks.
    const int kswz = (q4 ^ ((nn >> 1) & 3)) * 8;
    const unsigned short* kp0 = &Klds[nn * HD + kswz];
    const unsigned short* kp1 = &Klds[(16 + nn) * HD + kswz];
    const unsigned short* vp0 = &Vt[nn * VSTRIDE + q4 * 4];
    const unsigned short* vp1 = &Vt[(16 + nn) * VSTRIDE + q4 * 4];

    // ---- main K loop: 16 chunks of 32 keys; breadth-first qq-pairs ----
    for (int kc = 0; kc < 16; ++kc) {
        const int ko = kc * 32;
        const short8 kf0 = *(const short8*)(kp0 + ko * HD);
        const short8 kf1 = *(const short8*)(kp1 + ko * HD);
        short8 vf0, vf1;
        {
            FragU f0, f1;
            f0.v4[0] = *(const ushort4*)(vp0 + ko);
            f0.v4[1] = *(const ushort4*)(vp0 + ko + 16);
            f1.v4[0] = *(const ushort4*)(vp1 + ko);
            f1.v4[1] = *(const ushort4*)(vp1 + ko + 16);
            vf0 = f0.s; vf1 = f1.s;
        }

        __builtin_amdgcn_s_setprio(1);
        #pragma unroll
        for (int qp = 0; qp < 2; ++qp) {
            const int qa = qp * 2, qb = qp * 2 + 1;
            // 4 independent QK MFMAs issued together (pipe fills)
            floatx4 sa0 = __builtin_amdgcn_mfma_f32_16x16x32_bf16(kf0, qf[qa], zf, 0, 0, 0);
            floatx4 sa1 = __builtin_amdgcn_mfma_f32_16x16x32_bf16(kf1, qf[qa], zf, 0, 0, 0);
            floatx4 sb0 = __builtin_amdgcn_mfma_f32_16x16x32_bf16(kf0, qf[qb], zf, 0, 0, 0);
            floatx4 sb1 = __builtin_amdgcn_mfma_f32_16x16x32_bf16(kf1, qf[qb], zf, 0, 0, 0);
            if (mwin) {                              // wave-uniform branch (1/8 blocks)
                #pragma unroll
                for (int r = 0; r < 4; ++r) {
                    sa0[r] += mk[r]; sa1[r] += mk[r];
                    sb0[r] += mk[r]; sb1[r] += mk[r];
                }
            }
            // 16 independent exps (two 8-wide groups), same per-value order
            float pa[8], pb[8];
            #pragma unroll
            for (int r = 0; r < 4; ++r) {
                pa[r]     = __ocml_native_exp2_f32(sa0[r]);
                pa[4 + r] = __ocml_native_exp2_f32(sa1[r]);
                pb[r]     = __ocml_native_exp2_f32(sb0[r]);
                pb[4 + r] = __ocml_native_exp2_f32(sb1[r]);
            }
            rs[qa] += ((pa[0] + pa[1]) + (pa[2] + pa[3])) + ((pa[4] + pa[5]) + (pa[6] + pa[7]));
            rs[qb] += ((pb[0] + pb[1]) + (pb[2] + pb[3])) + ((pb[4] + pb[5]) + (pb[6] + pb[7]));
            FragU pfa, pfb;                          // truncation pack: 1 v_perm each
            pfa.u[0] = pk2t(pa[0], pa[1]); pfa.u[1] = pk2t(pa[2], pa[3]);
            pfa.u[2] = pk2t(pa[4], pa[5]); pfa.u[3] = pk2t(pa[6], pa[7]);
            pfb.u[0] = pk2t(pb[0], pb[1]); pfb.u[1] = pk2t(pb[2], pb[3]);
            pfb.u[2] = pk2t(pb[4], pb[5]); pfb.u[3] = pk2t(pb[6], pb[7]);
            // 4 PV MFMAs issued together
            acc[qa][0] = __builtin_amdgcn_mfma_f32_16x16x32_bf16(vf0, pfa.s, acc[qa][0], 0, 0, 0);
            acc[qa][1] = __builtin_amdgcn_mfma_f32_16x16x32_bf16(vf1, pfa.s, acc[qa][1], 0, 0, 0);
            acc[qb][0] = __builtin_amdgcn_mfma_f32_16x16x32_bf16(vf0, pfb.s, acc[qb][0], 0, 0, 0);
            acc[qb][1] = __builtin_amdgcn_mfma_f32_16x16x32_bf16(vf1, pfb.s, acc[qb][1], 0, 0, 0);
        }
        __builtin_amdgcn_s_setprio(0);
    }

    // ---- row sums across quads; lane-aligned with PV C-layout columns ----
    float inv[4];
    #pragma unroll
    for (int qq = 0; qq < 4; ++qq) {
        float v = rs[qq];
        v += __shfl_xor(v, 16);
        v += __shfl_xor(v, 32);
        inv[qq] = 1.0f / v;
    }

    // ---- epilogue: normalize, +conv bias, LePE 3x3 from Vt, store bf16 X ----
    #pragma unroll
    for (int qq = 0; qq < 4; ++qq) {
        const int t = qbase + qq * 16 + nn;
        const int h = t >> 3, wi = t & 7;
        #pragma unroll
        for (int nt = 0; nt < 2; ++nt) {
            const int chb = nt * 16 + q4 * 4;
            float o[4];
            #pragma unroll
            for (int r = 0; r < 4; ++r)
                o[r] = acc[qq][nt][r] * inv[qq] + cb[chb + r];
            #pragma unroll
            for (int dh = -1; dh <= 1; ++dh) {
                const int hh = h + dh;
                if (hh < 0 || hh >= RESO) continue;
                #pragma unroll
                for (int dw = -1; dw <= 1; ++dw) {
                    const int ww = wi + dw;
                    if (ww < 0 || ww >= 8) continue;
                    const int tj  = hh * 8 + ww;
                    const int wof = (dh + 1) * 3 + (dw + 1);
                    #pragma unroll
                    for (int r = 0; r < 4; ++r)
                        o[r] += cw[(chb + r) * 9 + wof] * bf2f(Vt[(chb + r) * VSTRIDE + tj]);
                }
            }
            ushort4 st;
            st.x = f2bf(o[0]); st.y = f2bf(o[1]); st.z = f2bf(o[2]); st.w = f2bf(o[3]);
            *(ushort4*)&X[((size_t)bw * WIN + t) * DIM + head * HD + chb] = st;
        }
    }
}

// ---------------------------------------------------------------------------
// Kernel 2 (v3, unchanged from r6): MFMA projection GEMM, permuted rows.
// r5/r6 established proj responds to traffic but not residency -> it is
// small (~10-20 us); the ~137 us E2E residual is mostly fixed harness
// overhead.  Keep v3 (same E2E as v1, finer-grained tail).
// ---------------------------------------------------------------------------
__global__ __launch_bounds__(256, 4)
void proj_mfma_kernel(const unsigned short* __restrict__ X,
                      const float* __restrict__ pw,
                      const float* __restrict__ pb,
                      float* __restrict__ out)
{
    __shared__ alignas(16) unsigned short Wl[64 * WPAD];   // 33.8 KB

    // XCD swizzle (1024 = 8 XCD x 128, bijective): XCD x owns m-chunks
    // [32x, 32x+32) x all 4 n-blocks; nblk varies fastest within the XCD.
    const int raw  = blockIdx.x;
    const int bx   = ((raw & 7) << 7) | (raw >> 3);
    const int mchk = bx >> 2;            // 0..255 -> 128 tokens each
    const int nblk = bx & 3;             // 0..3   -> 64 channels each
    const int tid  = threadIdx.x;
    const int n0   = nblk * 64;

    // ---- stage W[n0..n0+63][0..255] -> bf16 LDS (4 threads per row) ----
    {
        const int row = tid >> 2;
        const int cb0 = (tid & 3) * 64;
        #pragma unroll
        for (int c = 0; c < 64; c += 8) {
            const float4 w0 = *(const float4*)&pw[(size_t)(n0 + row) * DIM + cb0 + c];
            const float4 w1 = *(const float4*)&pw[(size_t)(n0 + row) * DIM + cb0 + c + 4];
            uint4 pk;
            pk.x = pk2(w0.x, w0.y); pk.y = pk2(w0.z, w0.w);
            pk.z = pk2(w1.x, w1.y); pk.w = pk2(w1.z, w1.w);
            *(uint4*)&Wl[row * WPAD + cb0 + c] = pk;
        }
    }
    __syncthreads();

    const int lane = tid & 63, wid = tid >> 6;
    const int q4 = lane >> 4, nn = lane & 15;
    const int m0 = mchk * 128 + wid * 32;        // 32 tokens per wave

    floatx4 acc[4][2];                            // [nt][mt]
    #pragma unroll
    for (int i = 0; i < 4; ++i)
        #pragma unroll
        for (int j = 0; j < 2; ++j)
            acc[i][j] = (floatx4){0.f, 0.f, 0.f, 0.f};

    for (int kk = 0; kk < 8; ++kk) {
        short8 af[4], bf[2];
        #pragma unroll
        for (int nt = 0; nt < 4; ++nt)
            af[nt] = *(const short8*)&Wl[(nt * 16 + nn) * WPAD + kk * 32 + q4 * 8];
        #pragma unroll
        for (int mt = 0; mt < 2; ++mt) {
            const int m = m0 + mt * 16 + nn;
            bf[mt] = *(const short8*)&X[(size_t)m * DIM + kk * 32 + q4 * 8];
        }
        #pragma unroll
        for (int nt = 0; nt < 4; ++nt)
            #pragma unroll
            for (int mt = 0; mt < 2; ++mt)
                acc[nt][mt] = __builtin_amdgcn_mfma_f32_16x16x32_bf16(af[nt], bf[mt], acc[nt][mt], 0, 0, 0);
    }

    // ---- bias + permuted store (float4 per lane per tile) ----
    float4 bias[4];
    #pragma unroll
    for (int nt = 0; nt < 4; ++nt)
        bias[nt] = *(const float4*)&pb[n0 + nt * 16 + q4 * 4];

    size_t rowoff[2];
    #pragma unroll
    for (int mt = 0; mt < 2; ++mt) {
        const int m  = m0 + mt * 16 + nn;
        const int bw = m >> 9, t = m & 511;
        const int bb = bw >> 3, wx = bw & 7, hh = t >> 3, wi = t & 7;
        rowoff[mt] = ((size_t)bb * SEQL + (size_t)hh * RESO + wx * 8 + wi) * DIM;
    }

    #pragma unroll
    for (int nt = 0; nt < 4; ++nt)
        #pragma unroll
        for (int mt = 0; mt < 2; ++mt) {
            float4 v;
            v.x = acc[nt][mt][0] + bias[nt].x;
            v.y = acc[nt][mt][1] + bias[nt].y;
            v.z = acc[nt][mt][2] + bias[nt].z;
            v.w = acc[nt][mt][3] + bias[nt].w;
            *(float4*)&out[rowoff[mt] + n0 + nt * 16 + q4 * 4] = v;
        }
}

extern "C" void kernel_launch(void* const* d_in, const int* in_sizes, int n_in,
                              void* d_out, int out_size, void* d_ws, size_t ws_size,
                              hipStream_t stream)
{
    const float* qkv    = (const float*)d_in[0];
    const float* scale  = (const float*)d_in[1];
    const float* proj_w = (const float*)d_in[2];
    const float* proj_b = (const float*)d_in[3];
    const float* conv_w = (const float*)d_in[4];
    const float* conv_b = (const float*)d_in[5];

    unsigned short* X = (unsigned short*)d_ws;   // 64*512*256 bf16 = 16 MiB

    attn_mfma_kernel<<<dim3(BATCH * NH * 8), dim3(512), 0, stream>>>(
        qkv, scale, conv_w, conv_b, X);

    proj_mfma_kernel<<<dim3(1024), dim3(256), 0, stream>>>(
        X, proj_w, proj_b, (float*)d_out);
}